// Round 1
// baseline (1657.063 us; speedup 1.0000x reference)
//
#include <hip/hip_runtime.h>
#include <hip/hip_bf16.h>

#define BATCH 256
#define D0 128
#define D1 512
#define D2 1024
#define NV 100000
#define EPSBN 0.8f
#define SLOPE 0.2f
#define BNT 160
#define KSTEP 64
#define NBLK 625            // NV / BNT
#define ONEHOT_N 128000000L // 256*5*100000

typedef __attribute__((ext_vector_type(4))) float f32x4;
typedef __attribute__((ext_vector_type(8))) short bf16x8;
typedef __attribute__((ext_vector_type(4))) short bf16x4;

__device__ __forceinline__ unsigned short f2bf(float x) {
    unsigned u = __float_as_uint(x);
    u += 0x7fffu + ((u >> 16) & 1u);        // RNE
    return (unsigned short)(u >> 16);
}
__device__ __forceinline__ float bf2f(unsigned short h) {
    return __uint_as_float(((unsigned)h) << 16);
}
__device__ __forceinline__ bool better(float v, int c, float V, int C) {
    return (v > V) || (v == V && c < C);
}

// maintain sorted-desc top5 in named regs v0..v4/c0..c4
#define INS(pv, pc) do { float _pv=(pv); int _pc=(pc); \
  if (better(_pv,_pc,v4,c4)) { \
    if (better(_pv,_pc,v0,c0))      { v4=v3;c4=c3; v3=v2;c3=c2; v2=v1;c2=c1; v1=v0;c1=c0; v0=_pv;c0=_pc; } \
    else if (better(_pv,_pc,v1,c1)) { v4=v3;c4=c3; v3=v2;c3=c2; v2=v1;c2=c1; v1=_pv;c1=_pc; } \
    else if (better(_pv,_pc,v2,c2)) { v4=v3;c4=c3; v3=v2;c3=c2; v2=_pv;c2=_pc; } \
    else if (better(_pv,_pc,v3,c3)) { v4=v3;c4=c3; v3=_pv;c3=_pc; } \
    else                            { v4=_pv;c4=_pc; } } } while(0)

#define TOP5_INIT float v0=-__builtin_inff(),v1=-__builtin_inff(),v2=-__builtin_inff(), \
                        v3=-__builtin_inff(),v4=-__builtin_inff(); \
                  int c0=0x7fffffff,c1=0x7fffffff,c2=0x7fffffff,c3=0x7fffffff,c4=0x7fffffff

// ---------- h0 = lrelu(z @ W0^T + b0), [256][512] ----------
__global__ __launch_bounds__(256) void k_h0(const float* __restrict__ z,
                                            const float* __restrict__ W0,
                                            const float* __restrict__ b0,
                                            float* __restrict__ h0) {
    int m = blockIdx.x;
    __shared__ float zrow[D0];
    if (threadIdx.x < D0) zrow[threadIdx.x] = z[m * D0 + threadIdx.x];
    __syncthreads();
    for (int j = threadIdx.x; j < D1; j += 256) {
        const f32x4* w4 = (const f32x4*)(W0 + j * D0);
        float acc = 0.f;
        #pragma unroll
        for (int k = 0; k < D0 / 4; k++) {
            f32x4 w = w4[k];
            acc += zrow[4*k]*w[0] + zrow[4*k+1]*w[1] + zrow[4*k+2]*w[2] + zrow[4*k+3]*w[3];
        }
        acc += b0[j];
        h0[m * D1 + j] = acc >= 0.f ? acc : SLOPE * acc;
    }
}

// ---------- h1_pre = h0 @ W1^T + b1, [256][1024]; 32 blocks x 8 rows ----------
__global__ __launch_bounds__(1024) void k_h1pre(const float* __restrict__ h0,
                                                const float* __restrict__ W1,
                                                const float* __restrict__ b1,
                                                float* __restrict__ h1p) {
    int mb = blockIdx.x * 8;
    int j = threadIdx.x;
    __shared__ float hr[8][D1];
    for (int i = threadIdx.x; i < 8 * D1; i += 1024)
        hr[i >> 9][i & 511] = h0[(mb + (i >> 9)) * D1 + (i & 511)];
    __syncthreads();
    float acc[8] = {0,0,0,0,0,0,0,0};
    const f32x4* w4 = (const f32x4*)(W1 + j * D1);
    for (int k = 0; k < D1 / 4; k++) {
        f32x4 w = w4[k];
        #pragma unroll
        for (int r = 0; r < 8; r++)
            acc[r] += hr[r][4*k]*w[0] + hr[r][4*k+1]*w[1] + hr[r][4*k+2]*w[2] + hr[r][4*k+3]*w[3];
    }
    float bb = b1[j];
    #pragma unroll
    for (int r = 0; r < 8; r++) h1p[(mb + r) * D2 + j] = acc[r] + bb;
}

// ---------- BN1 column stats ----------
__global__ __launch_bounds__(256) void k_bn1stats(const float* __restrict__ h1p,
                                                  float* __restrict__ meanv,
                                                  float* __restrict__ rstdv) {
    int j = blockIdx.x, t = threadIdx.x;
    float x = h1p[t * D2 + j];
    float s = x, q = x * x;
    #pragma unroll
    for (int o = 32; o > 0; o >>= 1) { s += __shfl_down(s, o, 64); q += __shfl_down(q, o, 64); }
    __shared__ float ss[4], qq[4];
    if ((t & 63) == 0) { ss[t >> 6] = s; qq[t >> 6] = q; }
    __syncthreads();
    if (t == 0) {
        float S = ss[0]+ss[1]+ss[2]+ss[3], Q = qq[0]+qq[1]+qq[2]+qq[3];
        float m = S * (1.f/BATCH), v = Q * (1.f/BATCH) - m * m;
        meanv[j] = m; rstdv[j] = rsqrtf(v + EPSBN);
    }
}

// ---------- apply BN1 + lrelu, split to bf16 hi/lo ----------
__global__ __launch_bounds__(256) void k_bn1apply(const float* __restrict__ h1p,
                                                  const float* __restrict__ meanv,
                                                  const float* __restrict__ rstdv,
                                                  const float* __restrict__ g1,
                                                  const float* __restrict__ be1,
                                                  unsigned short* __restrict__ Ahi,
                                                  unsigned short* __restrict__ Alo) {
    int id = blockIdx.x * 256 + threadIdx.x;
    int j = id & (D2 - 1);
    float x = h1p[id];
    float y = (x - meanv[j]) * rstdv[j] * g1[j] + be1[j];
    y = y >= 0.f ? y : SLOPE * y;
    unsigned short h = f2bf(y);
    unsigned short l = f2bf(y - bf2f(h));
    Ahi[id] = h; Alo[id] = l;
}

// ---------- zero the onehot region ----------
__global__ void k_zero(float* __restrict__ out, long n4) {
    long i = (long)blockIdx.x * blockDim.x + threadIdx.x;
    long stride = (long)gridDim.x * blockDim.x;
    f32x4* o = (f32x4*)out;
    f32x4 zz = {0.f, 0.f, 0.f, 0.f};
    for (; i < n4; i += stride) o[i] = zz;
}

// ---------- big GEMM2 + BN2 + per-block top5 ----------
// LDS map (bytes): Bh [160][64]bf16 @0 (20480); Bl @20480; psum[4][160] @40960;
// psq[4][160] @43520; cA[160] @46080; cB[160] @46720. rowtop[256][2][5]f2 aliases @0.
__global__ __launch_bounds__(512) void k_gemm2(const unsigned short* __restrict__ Ahi,
                                               const unsigned short* __restrict__ Alo,
                                               const float* __restrict__ W2,
                                               const float* __restrict__ g2,
                                               const float* __restrict__ be2,
                                               float2* __restrict__ cand) {
    __shared__ __align__(16) char smem[47360];
    const int tid = threadIdx.x;
    const int blk = blockIdx.x;
    const int n0 = blk * BNT;
    const int lane = tid & 63, w = tid >> 6;
    const int wm = w & 3, wn = w >> 2;
    const int l15 = lane & 15, lg = lane >> 4;

    f32x4 acc[4][5];
    f32x4 zz = {0.f, 0.f, 0.f, 0.f};
    #pragma unroll
    for (int a = 0; a < 4; a++)
        #pragma unroll
        for (int b = 0; b < 5; b++) acc[a][b] = zz;

    for (int kt = 0; kt < D2 / KSTEP; kt++) {
        // stage + convert W2 tile: 160 rows x 64 k fp32 -> bf16 hi/lo, XOR swizzle
        #pragma unroll
        for (int i = 0; i < 5; i++) {
            int f = tid + 512 * i;          // < 2560
            int row = f >> 4, kq = f & 15;
            const float* gp = W2 + (size_t)(n0 + row) * D2 + kt * KSTEP + kq * 4;
            f32x4 v = *(const f32x4*)gp;
            bf16x4 hv, lv;
            #pragma unroll
            for (int e = 0; e < 4; e++) {
                float x = v[e];
                unsigned short h = f2bf(x);
                hv[e] = (short)h;
                lv[e] = (short)f2bf(x - bf2f(h));
            }
            int boff = row * 128 + ((kq * 8) ^ ((row & 7) << 4));
            *(bf16x4*)(smem + boff) = hv;
            *(bf16x4*)(smem + 20480 + boff) = lv;
        }
        __syncthreads();
        #pragma unroll
        for (int ks = 0; ks < 2; ks++) {
            bf16x8 ah[4], al[4], bh[5], bl[5];
            #pragma unroll
            for (int mi = 0; mi < 4; mi++) {
                size_t aoff = (size_t)(wm * 64 + mi * 16 + l15) * D2 + kt * KSTEP + ks * 32 + lg * 8;
                ah[mi] = *(const bf16x8*)(Ahi + aoff);
                al[mi] = *(const bf16x8*)(Alo + aoff);
            }
            #pragma unroll
            for (int ni = 0; ni < 5; ni++) {
                int row = wn * 80 + ni * 16 + l15;
                int koffb = (ks * 32 + lg * 8) * 2;
                int boff = row * 128 + (koffb ^ ((row & 7) << 4));
                bh[ni] = *(const bf16x8*)(smem + boff);
                bl[ni] = *(const bf16x8*)(smem + 20480 + boff);
            }
            #pragma unroll
            for (int mi = 0; mi < 4; mi++)
                #pragma unroll
                for (int ni = 0; ni < 5; ni++) {
                    acc[mi][ni] = __builtin_amdgcn_mfma_f32_16x16x32_bf16(ah[mi], bh[ni], acc[mi][ni], 0, 0, 0);
                    acc[mi][ni] = __builtin_amdgcn_mfma_f32_16x16x32_bf16(ah[mi], bl[ni], acc[mi][ni], 0, 0, 0);
                    acc[mi][ni] = __builtin_amdgcn_mfma_f32_16x16x32_bf16(al[mi], bh[ni], acc[mi][ni], 0, 0, 0);
                }
        }
        __syncthreads();
    }

    // ---- BN2 column stats (per column over all 256 rows) ----
    float* psum = (float*)(smem + 40960);
    float* psq  = (float*)(smem + 43520);
    float* cAv  = (float*)(smem + 46080);
    float* cBv  = (float*)(smem + 46720);

    float s_[5], q_[5];
    #pragma unroll
    for (int ni = 0; ni < 5; ni++) {
        float s = 0.f, q = 0.f;
        #pragma unroll
        for (int mi = 0; mi < 4; mi++)
            #pragma unroll
            for (int r = 0; r < 4; r++) { float v = acc[mi][ni][r]; s += v; q += v * v; }
        s += __shfl_xor(s, 16, 64); q += __shfl_xor(q, 16, 64);
        s += __shfl_xor(s, 32, 64); q += __shfl_xor(q, 32, 64);
        s_[ni] = s; q_[ni] = q;
    }
    if (lg == 0) {
        #pragma unroll
        for (int ni = 0; ni < 5; ni++) {
            int col = wn * 80 + ni * 16 + l15;
            psum[wm * 160 + col] = s_[ni];
            psq [wm * 160 + col] = q_[ni];
        }
    }
    __syncthreads();
    if (tid < BNT) {
        float S = psum[tid] + psum[160 + tid] + psum[320 + tid] + psum[480 + tid];
        float Q = psq[tid]  + psq[160 + tid]  + psq[320 + tid]  + psq[480 + tid];
        float m = S * (1.f / BATCH), v = Q * (1.f / BATCH) - m * m;
        float rs = rsqrtf(v + EPSBN);
        float a = g2[n0 + tid] * rs;
        cAv[tid] = a;
        cBv[tid] = be2[n0 + tid] - m * a;
    }
    __syncthreads();

    // ---- fused top5 per row over this block's 160 cols ----
    float ca[5], cb[5]; int cc[5];
    #pragma unroll
    for (int ni = 0; ni < 5; ni++) {
        int col = wn * 80 + ni * 16 + l15;
        ca[ni] = cAv[col]; cb[ni] = cBv[col]; cc[ni] = n0 + col;
    }
    float2* rowtop = (float2*)smem;   // [256][2][5]
    #pragma unroll
    for (int mi = 0; mi < 4; mi++) {
        #pragma unroll
        for (int r = 0; r < 4; r++) {
            TOP5_INIT;
            #pragma unroll
            for (int ni = 0; ni < 5; ni++) {
                float pv = acc[mi][ni][r] * ca[ni] + cb[ni];
                INS(pv, cc[ni]);
            }
            // butterfly merge across the 16 lanes holding this row
            #pragma unroll
            for (int msk = 1; msk < 16; msk <<= 1) {
                float pv0=__shfl_xor(v0,msk,64), pv1=__shfl_xor(v1,msk,64), pv2=__shfl_xor(v2,msk,64),
                      pv3=__shfl_xor(v3,msk,64), pv4=__shfl_xor(v4,msk,64);
                int   pc0=__shfl_xor(c0,msk,64), pc1=__shfl_xor(c1,msk,64), pc2=__shfl_xor(c2,msk,64),
                      pc3=__shfl_xor(c3,msk,64), pc4=__shfl_xor(c4,msk,64);
                INS(pv0,pc0); INS(pv1,pc1); INS(pv2,pc2); INS(pv3,pc3); INS(pv4,pc4);
            }
            if (l15 == 0) {
                int rowl = wm * 64 + mi * 16 + lg * 4 + r;
                float2* p = rowtop + (rowl * 2 + wn) * 5;
                p[0] = make_float2(v0, __int_as_float(c0));
                p[1] = make_float2(v1, __int_as_float(c1));
                p[2] = make_float2(v2, __int_as_float(c2));
                p[3] = make_float2(v3, __int_as_float(c3));
                p[4] = make_float2(v4, __int_as_float(c4));
            }
        }
    }
    __syncthreads();
    if (tid < 256) {
        TOP5_INIT;
        const float2* pa = rowtop + tid * 10;
        #pragma unroll
        for (int k = 0; k < 10; k++) { float2 e = pa[k]; INS(e.x, __float_as_int(e.y)); }
        float2* cw = cand + ((size_t)tid * NBLK + blk) * 5;
        cw[0] = make_float2(v0, __int_as_float(c0));
        cw[1] = make_float2(v1, __int_as_float(c1));
        cw[2] = make_float2(v2, __int_as_float(c2));
        cw[3] = make_float2(v3, __int_as_float(c3));
        cw[4] = make_float2(v4, __int_as_float(c4));
    }
}

// ---------- merge candidates per row, write idx + onehot ones ----------
__global__ __launch_bounds__(256) void k_merge(const float2* __restrict__ cand,
                                               float* __restrict__ out) {
    int row = blockIdx.x, tid = threadIdx.x;
    TOP5_INIT;
    const float2* cr = cand + (size_t)row * (NBLK * 5);
    for (int i = tid; i < NBLK * 5; i += 256) {
        float2 e = cr[i];
        INS(e.x, __float_as_int(e.y));
    }
    __shared__ float2 ls[256 * 5];
    float2* mine = ls + tid * 5;
    mine[0]=make_float2(v0,__int_as_float(c0)); mine[1]=make_float2(v1,__int_as_float(c1));
    mine[2]=make_float2(v2,__int_as_float(c2)); mine[3]=make_float2(v3,__int_as_float(c3));
    mine[4]=make_float2(v4,__int_as_float(c4));
    __syncthreads();
    for (int s = 128; s > 0; s >>= 1) {
        if (tid < s) {
            const float2* pb = ls + (tid + s) * 5;
            #pragma unroll
            for (int k = 0; k < 5; k++) { float2 e = pb[k]; INS(e.x, __float_as_int(e.y)); }
            mine[0]=make_float2(v0,__int_as_float(c0)); mine[1]=make_float2(v1,__int_as_float(c1));
            mine[2]=make_float2(v2,__int_as_float(c2)); mine[3]=make_float2(v3,__int_as_float(c3));
            mine[4]=make_float2(v4,__int_as_float(c4));
        }
        __syncthreads();
    }
    if (tid == 0) {
        int cs[5] = {c0, c1, c2, c3, c4};
        #pragma unroll
        for (int k = 0; k < 5; k++) {
            out[ONEHOT_N + row * 5 + k] = (float)cs[k];
            out[(size_t)row * 500000 + (size_t)k * 100000 + cs[k]] = 1.0f;
        }
    }
}

extern "C" void kernel_launch(void* const* d_in, const int* in_sizes, int n_in,
                              void* d_out, int out_size, void* d_ws, size_t ws_size,
                              hipStream_t stream) {
    const float* z   = (const float*)d_in[0];
    const float* W0  = (const float*)d_in[1];
    const float* b0  = (const float*)d_in[2];
    const float* W1  = (const float*)d_in[3];
    const float* b1  = (const float*)d_in[4];
    const float* g1  = (const float*)d_in[5];
    const float* be1 = (const float*)d_in[6];
    const float* W2  = (const float*)d_in[7];
    // d_in[8] = b2: cancels exactly under BN (mean subtraction) — unused
    const float* g2  = (const float*)d_in[9];
    const float* be2 = (const float*)d_in[10];

    char* ws = (char*)d_ws;
    float* h0            = (float*)(ws);                 // 524288 B
    float* h1p           = (float*)(ws + 524288);        // 1048576 B
    float* meanv         = (float*)(ws + 1572864);       // 4096 B
    float* rstdv         = (float*)(ws + 1576960);       // 4096 B
    unsigned short* Ahi  = (unsigned short*)(ws + 1581056); // 524288 B
    unsigned short* Alo  = (unsigned short*)(ws + 2105344); // 524288 B
    float2* cand         = (float2*)(ws + 2629632);      // 6400000 B

    float* out = (float*)d_out;

    k_h0      <<<BATCH, 256, 0, stream>>>(z, W0, b0, h0);
    k_h1pre   <<<32, 1024, 0, stream>>>(h0, W1, b1, h1p);
    k_bn1stats<<<D2, 256, 0, stream>>>(h1p, meanv, rstdv);
    k_bn1apply<<<(BATCH * D2) / 256, 256, 0, stream>>>(h1p, meanv, rstdv, g1, be1, Ahi, Alo);
    k_zero    <<<2048, 256, 0, stream>>>(out, ONEHOT_N / 4);
    k_gemm2   <<<NBLK, 512, 0, stream>>>(Ahi, Alo, W2, g2, be2, cand);
    k_merge   <<<BATCH, 256, 0, stream>>>(cand, out);
}